// Round 2
// baseline (239.842 us; speedup 1.0000x reference)
//
#include <hip/hip_runtime.h>

#define BB 256
#define LL 500
#define EE 300
#define HH 10
#define KK 5
#define NF 50          // K*H output features
#define NT 512         // 8 waves
#define NWAVE 8

#define MP 512         // padded M rows per batch
#define CK 32          // K-chunk per stage
#define NCH 10         // 10*32 = 320 (K zero-padded 300->320)
#define BP 328         // Bt row stride (bf16): 320 + 8 pad
#define PP 53          // proj row stride (fp32), odd -> conflict-free
#define NA4 3750       // float4 in aspProj (15000 floats)

// LDS overlay (bytes). A is never staged in LDS (fragments come straight
// from global), so Bt sits at 0 and s_d overlays it post-GEMM.
#define B_BYTES  (64 * BP * 2)                 // 41984
#define PROJ_OFF B_BYTES                       // 41984 (16B aligned)
#define RED_OFF  (PROJ_OFF + MP * PP * 4)      // 150528
#define REP_OFF  (RED_OFF + KK * NWAVE * 4)    // 150688
#define EMB_OFF  (REP_OFF + NWAVE * NF * 4)    // 152288
#define SMEM_BYTES (EMB_OFF + KK * 3 * HH * 4) // 152888 < 163840

typedef __attribute__((ext_vector_type(8))) short short8;
typedef __attribute__((ext_vector_type(4))) float f32x4;

__device__ __forceinline__ unsigned int f2bf(float x) {
    unsigned int u = __float_as_uint(x);
    return (u + 0x7FFFu + ((u >> 16) & 1u)) >> 16;   // RNE fp32->bf16 (low 16)
}

__device__ __forceinline__ short8 pack8(float4 a, float4 b) {
    short8 r;
    r[0] = (short)f2bf(a.x); r[1] = (short)f2bf(a.y);
    r[2] = (short)f2bf(a.z); r[3] = (short)f2bf(a.w);
    r[4] = (short)f2bf(b.x); r[5] = (short)f2bf(b.y);
    r[6] = (short)f2bf(b.z); r[7] = (short)f2bf(b.w);
    return r;
}

__global__ __launch_bounds__(NT, 2) void anr_mfma4(
    const float* __restrict__ review,    // (B, L, E)
    const float* __restrict__ aspProj,   // (K, E, H)
    const float* __restrict__ aspEmbed,  // (K, 3H)
    float* __restrict__ out)             // [attn (B,K,L)] ++ [rep (B,K,H)]
{
    __shared__ __align__(16) char smem[SMEM_BYTES];
    short* B16   = (short*)smem;                  // Bt[64][BP] bf16, zero-padded
    float* s_d   = (float*)smem;                  // overlays B16 (epilogue only)
    float* proj  = (float*)(smem + PROJ_OFF);
    float* s_red = (float*)(smem + RED_OFF);
    float* s_rep = (float*)(smem + REP_OFF);
    float* s_emb = (float*)(smem + EMB_OFF);

    const int tid  = threadIdx.x;
    const int b    = blockIdx.x;
    const int lane = tid & 63;
    const int w    = tid >> 6;
    const int quad = lane >> 4;
    const int m16  = lane & 15;

    // ---- phase 0: zero Bt ----
    for (int j = tid; j < B_BYTES / 4; j += NT)
        ((int*)smem)[j] = 0;

    // ---- phase 1: issue all global loads early (overlap the barrier) ----
    const float4* ap4 = (const float4*)aspProj;
    float4 bt[8];
#pragma unroll
    for (int i = 0; i < 8; ++i) {
        int idx = tid + NT * i;
        bt[i] = ap4[(idx < NA4) ? idx : (NA4 - 1)];
    }
    float embv = aspEmbed[(tid < KK * 3 * HH) ? tid : 0];

    // per-thread A row pointers matching the MFMA A-fragment layout:
    // lane (quad,m16) of wave w, sub-tile mi holds row w*64+mi*16+m16,
    // k = quad*8 .. quad*8+7 (two consecutive float4 in global memory).
    const float* revb = review + (size_t)b * LL * EE;
    const float* ar[4];
#pragma unroll
    for (int mi = 0; mi < 4; ++mi) {
        int r = w * 64 + mi * 16 + m16;
        ar[mi] = revb + (size_t)((r < LL) ? r : (LL - 1)) * EE + quad * 8;
    }
    float4 fc[4][2], fn[4][2];
#pragma unroll
    for (int mi = 0; mi < 4; ++mi) {
        fc[mi][0] = *(const float4*)(ar[mi] + 0);
        fc[mi][1] = *(const float4*)(ar[mi] + 4);
    }

    __syncthreads();   // zeroing done

    // scatter Bt (write-guard only; loads were already in flight)
#pragma unroll
    for (int i = 0; i < 8; ++i) {
        int idx = tid + NT * i;
        if (idx < NA4) {
            float vv[4] = {bt[i].x, bt[i].y, bt[i].z, bt[i].w};
#pragma unroll
            for (int cm = 0; cm < 4; ++cm) {
                int jj   = 4 * idx + cm;                 // < 15000
                int kasp = jj / (EE * HH);
                int rr   = jj - kasp * (EE * HH);
                int e    = rr / HH;
                int h    = rr - e * HH;
                B16[(kasp * HH + h) * BP + e] = (short)f2bf(vv[cm]);
            }
        }
    }
    if (tid < KK * 3 * HH) s_emb[tid] = embv;
    __syncthreads();   // Bt ready; NO more barriers until after the GEMM

    // ---- GEMM main loop: A from global regs, B LDS-resident, barrier-free ----
    f32x4 acc[4][4];
#pragma unroll
    for (int mi = 0; mi < 4; ++mi)
#pragma unroll
        for (int ni = 0; ni < 4; ++ni)
            acc[mi][ni] = (f32x4){0.f, 0.f, 0.f, 0.f};

#pragma unroll
    for (int c = 0; c < NCH - 1; ++c) {
        // prefetch chunk c+1 into fn
        if (c < NCH - 2) {
#pragma unroll
            for (int mi = 0; mi < 4; ++mi) {
                fn[mi][0] = *(const float4*)(ar[mi] + (c + 1) * CK);
                fn[mi][1] = *(const float4*)(ar[mi] + (c + 1) * CK + 4);
            }
        } else {
            // tail chunk 9: k = 288 + quad*8 + j. Real data ends at k=300;
            // B rows 300..319 are zero, so A only needs to be (a) in-bounds
            // and (b) exactly zero where its k-slot multiplies a REAL B row.
            // quad0: k 288..295 full; quad1: k 296..299 real + 300..303 zero;
            // quads 2,3: k>=304 all zero (no load).
            const float4 z4 = {0.f, 0.f, 0.f, 0.f};
#pragma unroll
            for (int mi = 0; mi < 4; ++mi) {
                fn[mi][0] = (quad < 2) ? *(const float4*)(ar[mi] + (NCH - 1) * CK) : z4;
                fn[mi][1] = (quad < 1) ? *(const float4*)(ar[mi] + (NCH - 1) * CK + 4) : z4;
            }
        }
        short8 bf[4], af[4];
#pragma unroll
        for (int ni = 0; ni < 4; ++ni)
            bf[ni] = *(const short8*)&B16[(ni * 16 + m16) * BP + c * CK + quad * 8];
#pragma unroll
        for (int mi = 0; mi < 4; ++mi)
            af[mi] = pack8(fc[mi][0], fc[mi][1]);
#pragma unroll
        for (int mi = 0; mi < 4; ++mi)
#pragma unroll
            for (int ni = 0; ni < 4; ++ni)
                acc[mi][ni] = __builtin_amdgcn_mfma_f32_16x16x32_bf16(
                    af[mi], bf[ni], acc[mi][ni], 0, 0, 0);
#pragma unroll
        for (int mi = 0; mi < 4; ++mi) {
            fc[mi][0] = fn[mi][0];
            fc[mi][1] = fn[mi][1];
        }
    }
    {   // tail chunk
        const int c = NCH - 1;
        short8 bf[4], af[4];
#pragma unroll
        for (int ni = 0; ni < 4; ++ni)
            bf[ni] = *(const short8*)&B16[(ni * 16 + m16) * BP + c * CK + quad * 8];
#pragma unroll
        for (int mi = 0; mi < 4; ++mi)
            af[mi] = pack8(fc[mi][0], fc[mi][1]);
#pragma unroll
        for (int mi = 0; mi < 4; ++mi)
#pragma unroll
            for (int ni = 0; ni < 4; ++ni)
                acc[mi][ni] = __builtin_amdgcn_mfma_f32_16x16x32_bf16(
                    af[mi], bf[ni], acc[mi][ni], 0, 0, 0);
    }

    // ---- C fragments -> proj LDS (C/D: col = lane&15, row = quad*4 + reg) ----
    // proj region is disjoint from B16 and rows are wave-exclusive: no barrier
    // needed before the writes, one after.
#pragma unroll
    for (int mi = 0; mi < 4; ++mi) {
#pragma unroll
        for (int ni = 0; ni < 4; ++ni) {
            int col = ni * 16 + m16;
            if (col < NF) {
                int row = w * 64 + mi * 16 + quad * 4;
#pragma unroll
                for (int r = 0; r < 4; ++r)
                    proj[(row + r) * PP + col] = acc[mi][ni][r];
            }
        }
    }
    __syncthreads();   // all GEMM + proj writes done; B16 dead -> s_d may overlay

    // ---- epilogue: thread = one sequence position l ----
    const int l  = tid;
    const bool vl = (l < LL);            // pad rows contain garbage -> mask results

    float pr[NF];
#pragma unroll
    for (int f = 0; f < NF; ++f) pr[f] = proj[l * PP + f];

    float d0[KK], d1[KK], d2[KK];
#pragma unroll
    for (int k = 0; k < KK; ++k) {
        float a0 = 0.f, a1 = 0.f, a2 = 0.f;
#pragma unroll
        for (int h = 0; h < HH; ++h) {
            float x = pr[k * HH + h];
            a0 = fmaf(x, s_emb[k * 3 * HH + 3 * h + 0], a0);
            a1 = fmaf(x, s_emb[k * 3 * HH + 3 * h + 1], a1);
            a2 = fmaf(x, s_emb[k * 3 * HH + 3 * h + 2], a2);
        }
        d0[k] = vl ? a0 : 0.f;           // mask garbage pad rows (values only)
        d1[k] = vl ? a1 : 0.f;
        d2[k] = vl ? a2 : 0.f;
    }
#pragma unroll
    for (int k = 0; k < KK; ++k) {
        s_d[(0 * KK + k) * MP + l] = d0[k];
        s_d[(1 * KK + k) * MP + l] = d1[k];
        s_d[(2 * KK + k) * MP + l] = d2[k];
    }
    __syncthreads();

    const int lp1 = (l + 1 < MP) ? l + 1 : MP - 1;
    float sc[KK];
#pragma unroll
    for (int k = 0; k < KK; ++k) {
        float t0 = (l >= 1) ? s_d[(0 * KK + k) * MP + l - 1] : 0.f;
        float t1 = s_d[(1 * KK + k) * MP + l];
        float t2 = s_d[(2 * KK + k) * MP + lp1];
        sc[k] = vl ? (t0 + t1 + t2) : -1e30f;
    }

    float mx[KK];
#pragma unroll
    for (int k = 0; k < KK; ++k) {
        float m = sc[k];
        for (int s = 32; s > 0; s >>= 1) m = fmaxf(m, __shfl_xor(m, s, 64));
        if (lane == 0) s_red[k * NWAVE + w] = m;
    }
    __syncthreads();
#pragma unroll
    for (int k = 0; k < KK; ++k) {
        float m = s_red[k * NWAVE + 0];
#pragma unroll
        for (int ww = 1; ww < NWAVE; ++ww) m = fmaxf(m, s_red[k * NWAVE + ww]);
        mx[k] = m;
    }
    __syncthreads();
    float ex[KK], sm[KK];
#pragma unroll
    for (int k = 0; k < KK; ++k) {
        ex[k] = __expf(sc[k] - mx[k]);
        float s = ex[k];
        for (int sh = 32; sh > 0; sh >>= 1) s += __shfl_xor(s, sh, 64);
        if (lane == 0) s_red[k * NWAVE + w] = s;
    }
    __syncthreads();
#pragma unroll
    for (int k = 0; k < KK; ++k) {
        float s = 0.f;
#pragma unroll
        for (int ww = 0; ww < NWAVE; ++ww) s += s_red[k * NWAVE + ww];
        sm[k] = s;
    }

#pragma unroll
    for (int k = 0; k < KK; ++k) {
        float wk = ex[k] / sm[k];
        if (vl) out[((size_t)b * KK + k) * LL + l] = wk;
#pragma unroll
        for (int h = 0; h < HH; ++h) {
            float v = pr[k * HH + h] * wk;   // pads: garbage * 0 = 0 (finite)
            for (int sh = 32; sh > 0; sh >>= 1) v += __shfl_xor(v, sh, 64);
            if (lane == 0) s_rep[w * NF + k * HH + h] = v;
        }
    }
    __syncthreads();
    if (tid < NF) {
        float s = 0.f;
#pragma unroll
        for (int ww = 0; ww < NWAVE; ++ww) s += s_rep[ww * NF + tid];
        out[(size_t)BB * KK * LL + (size_t)b * NF + tid] = s;
    }
}

extern "C" void kernel_launch(void* const* d_in, const int* in_sizes, int n_in,
                              void* d_out, int out_size, void* d_ws, size_t ws_size,
                              hipStream_t stream) {
    const float* review   = (const float*)d_in[0];  // (B,L,E)
    const float* aspProj  = (const float*)d_in[1];  // (K,E,H)
    const float* aspEmbed = (const float*)d_in[2];  // (K,3H)
    float* out = (float*)d_out;

    anr_mfma4<<<dim3(BB), dim3(NT), 0, stream>>>(review, aspProj, aspEmbed, out);
}

// Round 3
// 239.578 us; speedup vs baseline: 1.0011x; 1.0011x over previous
//
#include <hip/hip_runtime.h>

#define BB 256
#define LL 500
#define EE 300
#define HH 10
#define KK 5
#define NF 50          // K*H output features
#define NT 512         // 8 waves
#define NWAVE 8

#define MP 512         // padded M rows per batch
#define CK 32          // K-chunk (MFMA K)
#define NCH 10         // 10*32 = 320 (K zero-padded 300->320)
#define BP 328         // Bt row stride (bf16): 320 + 8 pad
#define PP 53          // proj row stride (fp32), odd -> conflict-free
#define NA4 3750       // float4 in aspProj (15000 floats)

#define NG 16          // M-groups of 32 rows
#define GROWS 32
#define G_BYTES (GROWS * EE * 4)     // 38400 contiguous bytes per group
#define W_BYTES (G_BYTES / NWAVE)    // 4800 per wave: 4 full 1KB DMAs + 44-lane partial
#define REV_BYTES (LL * EE * 4)      // 600000 per batch

// LDS overlay (bytes)
#define B_BYTES   (64 * BP * 2)                // 41984
#define STG_OFF   B_BYTES                      // stage bufs overlay proj region
#define STG_STRIDE (G_BYTES + 128)             // 38528 (128B zeroed tail pad)
#define PROJ_OFF  STG_OFF                      // proj reuses stage region post-GEMM
#define RED_OFF   (STG_OFF + 3 * STG_STRIDE)   // 157568
#define REP_OFF   (RED_OFF + KK * NWAVE * 4)   // 157728
#define EMB_OFF   (REP_OFF + NWAVE * NF * 4)   // 159328
#define SMEM_BYTES (EMB_OFF + KK * 3 * HH * 4) // 159928 < 163840

typedef __attribute__((ext_vector_type(8))) short short8;
typedef __attribute__((ext_vector_type(4))) float f32x4;

__device__ __forceinline__ unsigned int f2bf(float x) {
    unsigned int u = __float_as_uint(x);
    return (u + 0x7FFFu + ((u >> 16) & 1u)) >> 16;   // RNE fp32->bf16 (low 16)
}

__device__ __forceinline__ short8 pack8(float4 a, float4 b) {
    short8 r;
    r[0] = (short)f2bf(a.x); r[1] = (short)f2bf(a.y);
    r[2] = (short)f2bf(a.z); r[3] = (short)f2bf(a.w);
    r[4] = (short)f2bf(b.x); r[5] = (short)f2bf(b.y);
    r[6] = (short)f2bf(b.z); r[7] = (short)f2bf(b.w);
    return r;
}

// Stage group g (32 rows, 38400 B contiguous) into buf (g%3) via async DMA.
// Each wave covers [w*4800, w*4800+4800): 4 full 1KB instrs + one 44-lane 704B.
// Per-lane GLOBAL addr arbitrary (clamped to batch end); LDS dest uniform base,
// HW adds lane*16 (m104/m108 semantics).
__device__ __forceinline__ void stage_grp(const char* revb, char* smem,
                                          int g, int w, int lane) {
    char* ldsb = smem + STG_OFF + (g % 3) * STG_STRIDE + w * W_BYTES;
    const char* gs = revb + (size_t)g * G_BYTES + (size_t)w * W_BYTES;
    const char* glim = revb + (REV_BYTES - 16);
#pragma unroll
    for (int j = 0; j < 5; ++j) {
        if (j < 4 || lane < 44) {
            const char* ga = gs + j * 1024 + lane * 16;
            if (ga > glim) ga = glim;     // rows >=500 garbage-finite, masked later
            __builtin_amdgcn_global_load_lds(
                (const __attribute__((address_space(1))) void*)ga,
                (__attribute__((address_space(3))) void*)(ldsb + j * 1024),
                16, 0, 0);
        }
    }
}

__global__ __launch_bounds__(NT, 2) void anr_mfma5(
    const float* __restrict__ review,    // (B, L, E)
    const float* __restrict__ aspProj,   // (K, E, H)
    const float* __restrict__ aspEmbed,  // (K, 3H)
    float* __restrict__ out)             // [attn (B,K,L)] ++ [rep (B,K,H)]
{
    __shared__ __align__(16) char smem[SMEM_BYTES];
    short* B16   = (short*)smem;                  // Bt[64][BP] bf16, zero-padded
    float* s_d   = (float*)smem;                  // overlays B16 (epilogue only)
    float* proj  = (float*)(smem + PROJ_OFF);     // overlays stage bufs (post-GEMM)
    float* s_red = (float*)(smem + RED_OFF);
    float* s_rep = (float*)(smem + REP_OFF);
    float* s_emb = (float*)(smem + EMB_OFF);

    const int tid  = threadIdx.x;
    const int b    = blockIdx.x;
    const int lane = tid & 63;
    const int w    = tid >> 6;
    const int quad = lane >> 4;
    const int m16  = lane & 15;
    const char* revb = (const char*)(review + (size_t)b * LL * EE);

    // ---- phase 1: issue param loads first (latency overlaps zeroing) ----
    const float4* ap4 = (const float4*)aspProj;
    float4 bt[8];
#pragma unroll
    for (int i = 0; i < 8; ++i) {
        int idx = tid + NT * i;
        bt[i] = ap4[(idx < NA4) ? idx : (NA4 - 1)];
    }
    float embv = aspEmbed[(tid < KK * 3 * HH) ? tid : 0];

    // ---- phase 0: zero Bt + the 3 stage-buffer tail pads (k/row overreads) ----
    for (int j = tid; j < B_BYTES / 4; j += NT)
        ((int*)smem)[j] = 0;
    if (tid < 96) {
        int bi = tid >> 5, wi = tid & 31;
        ((int*)(smem + STG_OFF + bi * STG_STRIDE + G_BYTES))[wi] = 0;
    }
    __syncthreads();   // zero visible (drains bt loads too; prologue-only cost)

    // kick off the DMA pipeline before the VALU-heavy scatter
    stage_grp(revb, smem, 0, w, lane);
    stage_grp(revb, smem, 1, w, lane);

    // scatter Bt (bf16, feature-major rows, k columns)
#pragma unroll
    for (int i = 0; i < 8; ++i) {
        int idx = tid + NT * i;
        if (idx < NA4) {
            float vv[4] = {bt[i].x, bt[i].y, bt[i].z, bt[i].w};
#pragma unroll
            for (int cm = 0; cm < 4; ++cm) {
                int jj   = 4 * idx + cm;                 // < 15000
                int kasp = jj / (EE * HH);
                int rr   = jj - kasp * (EE * HH);
                int e    = rr / HH;
                int h    = rr - e * HH;
                B16[(kasp * HH + h) * BP + e] = (short)f2bf(vv[cm]);
            }
        }
    }
    if (tid < KK * 3 * HH) s_emb[tid] = embv;
    asm volatile("s_waitcnt lgkmcnt(0)" ::: "memory");  // own ds_writes done pre-barrier

    // ---- GEMM: depth-2 DMA pipeline over 16 M-groups, counted vmcnt ----
    // wave w owns tile (mi2 = w>>2, ni = w&3) of each group's 32x50 output.
    f32x4 acc[NG];
#pragma unroll
    for (int g = 0; g < NG; ++g) acc[g] = (f32x4){0.f, 0.f, 0.f, 0.f};

    const int arow_off = ((w >> 2) * 16 + m16) * (EE * 4) + quad * 32;
    const int brow_off = ((w & 3) * 16 + m16) * BP;

#pragma unroll
    for (int g = 0; g < NG; ++g) {
        // wait own group-g DMAs (5 oldest); keep group g+1's 5 in flight
        if (g < NG - 1) asm volatile("s_waitcnt vmcnt(5)" ::: "memory");
        else            asm volatile("s_waitcnt vmcnt(0)" ::: "memory");
        __builtin_amdgcn_s_barrier();   // all waves: group g staged (+B16 on g=0)

        const char* ab = smem + STG_OFF + (g % 3) * STG_STRIDE + arow_off;
#pragma unroll 2
        for (int c = 0; c < NCH; ++c) {
            // tail chunk c=9 overreads into next row / zeroed pad; those k-slots
            // multiply B16 rows >=300 which are zero.
            float4 a0 = *(const float4*)(ab + c * 128);
            float4 a1 = *(const float4*)(ab + c * 128 + 16);
            short8 af = pack8(a0, a1);
            short8 bf = *(const short8*)&B16[brow_off + c * CK + quad * 8];
            acc[g] = __builtin_amdgcn_mfma_f32_16x16x32_bf16(af, bf, acc[g], 0, 0, 0);
        }
        // prefetch group g+2 into the buffer consumed at g-1 (all waves have
        // passed this iteration's barrier, so g-1's consume is complete)
        if (g + 2 < NG) stage_grp(revb, smem, g + 2, w, lane);
    }
    __syncthreads();   // all consumes done; stage region dies -> proj may overlay

    // ---- C fragments -> proj LDS (C/D: col = lane&15, row = quad*4 + reg) ----
#pragma unroll
    for (int g = 0; g < NG; ++g) {
        int col = (w & 3) * 16 + m16;
        if (col < NF) {
            int row = g * GROWS + (w >> 2) * 16 + quad * 4;
#pragma unroll
            for (int r = 0; r < 4; ++r)
                proj[(row + r) * PP + col] = acc[g][r];
        }
    }
    __syncthreads();

    // ---- epilogue: thread = one sequence position l ----
    const int l  = tid;
    const bool vl = (l < LL);            // pad rows contain garbage -> mask results

    float pr[NF];
#pragma unroll
    for (int f = 0; f < NF; ++f) pr[f] = proj[l * PP + f];

    float d0[KK], d1[KK], d2[KK];
#pragma unroll
    for (int k = 0; k < KK; ++k) {
        float a0 = 0.f, a1 = 0.f, a2 = 0.f;
#pragma unroll
        for (int h = 0; h < HH; ++h) {
            float x = pr[k * HH + h];
            a0 = fmaf(x, s_emb[k * 3 * HH + 3 * h + 0], a0);
            a1 = fmaf(x, s_emb[k * 3 * HH + 3 * h + 1], a1);
            a2 = fmaf(x, s_emb[k * 3 * HH + 3 * h + 2], a2);
        }
        d0[k] = vl ? a0 : 0.f;           // mask garbage pad rows (values only)
        d1[k] = vl ? a1 : 0.f;
        d2[k] = vl ? a2 : 0.f;
    }
#pragma unroll
    for (int k = 0; k < KK; ++k) {
        s_d[(0 * KK + k) * MP + l] = d0[k];
        s_d[(1 * KK + k) * MP + l] = d1[k];
        s_d[(2 * KK + k) * MP + l] = d2[k];
    }
    __syncthreads();

    const int lp1 = (l + 1 < MP) ? l + 1 : MP - 1;
    float sc[KK];
#pragma unroll
    for (int k = 0; k < KK; ++k) {
        float t0 = (l >= 1) ? s_d[(0 * KK + k) * MP + l - 1] : 0.f;
        float t1 = s_d[(1 * KK + k) * MP + l];
        float t2 = s_d[(2 * KK + k) * MP + lp1];
        sc[k] = vl ? (t0 + t1 + t2) : -1e30f;
    }

    float mx[KK];
#pragma unroll
    for (int k = 0; k < KK; ++k) {
        float m = sc[k];
        for (int s = 32; s > 0; s >>= 1) m = fmaxf(m, __shfl_xor(m, s, 64));
        if (lane == 0) s_red[k * NWAVE + w] = m;
    }
    __syncthreads();
#pragma unroll
    for (int k = 0; k < KK; ++k) {
        float m = s_red[k * NWAVE + 0];
#pragma unroll
        for (int ww = 1; ww < NWAVE; ++ww) m = fmaxf(m, s_red[k * NWAVE + ww]);
        mx[k] = m;
    }
    __syncthreads();
    float ex[KK], sm[KK];
#pragma unroll
    for (int k = 0; k < KK; ++k) {
        ex[k] = __expf(sc[k] - mx[k]);
        float s = ex[k];
        for (int sh = 32; sh > 0; sh >>= 1) s += __shfl_xor(s, sh, 64);
        if (lane == 0) s_red[k * NWAVE + w] = s;
    }
    __syncthreads();
#pragma unroll
    for (int k = 0; k < KK; ++k) {
        float s = 0.f;
#pragma unroll
        for (int ww = 0; ww < NWAVE; ++ww) s += s_red[k * NWAVE + ww];
        sm[k] = s;
    }

#pragma unroll
    for (int k = 0; k < KK; ++k) {
        float wk = ex[k] / sm[k];
        if (vl) out[((size_t)b * KK + k) * LL + l] = wk;
#pragma unroll
        for (int h = 0; h < HH; ++h) {
            float v = pr[k * HH + h] * wk;   // pads: garbage * 0 = 0 (finite)
            for (int sh = 32; sh > 0; sh >>= 1) v += __shfl_xor(v, sh, 64);
            if (lane == 0) s_rep[w * NF + k * HH + h] = v;
        }
    }
    __syncthreads();
    if (tid < NF) {
        float s = 0.f;
#pragma unroll
        for (int ww = 0; ww < NWAVE; ++ww) s += s_rep[ww * NF + tid];
        out[(size_t)BB * KK * LL + (size_t)b * NF + tid] = s;
    }
}

extern "C" void kernel_launch(void* const* d_in, const int* in_sizes, int n_in,
                              void* d_out, int out_size, void* d_ws, size_t ws_size,
                              hipStream_t stream) {
    const float* review   = (const float*)d_in[0];  // (B,L,E)
    const float* aspProj  = (const float*)d_in[1];  // (K,E,H)
    const float* aspEmbed = (const float*)d_in[2];  // (K,3H)
    float* out = (float*)d_out;

    anr_mfma5<<<dim3(BB), dim3(NT), 0, stream>>>(review, aspProj, aspEmbed, out);
}